// Round 5
// baseline (234.883 us; speedup 1.0000x reference)
//
#include <hip/hip_runtime.h>

#define NNODES 50000
#define CIN    128
#define COUT   256
#define KTOT   256   // 2*CIN

typedef float  f32x4  __attribute__((ext_vector_type(4)));
typedef short  bf16x8 __attribute__((ext_vector_type(8)));

#define GLOAD16(gptr, lptr) __builtin_amdgcn_global_load_lds(                      \
    (const __attribute__((address_space(1))) void*)(gptr),                         \
    (__attribute__((address_space(3))) void*)(lptr), 16, 0, 0)

__device__ __forceinline__ unsigned short f2bf(float f) {
    union { float f; unsigned int u; } v; v.f = f;
    unsigned int r = v.u + 0x7FFFu + ((v.u >> 16) & 1u);   // RNE
    return (unsigned short)(r >> 16);
}
__device__ __forceinline__ float bf2f(unsigned short u) {
    return __uint_as_float((unsigned int)u << 16);
}

// ---------------------------------------------------------------------------
// prep: convert x -> bf16 into xcat[:,0:128], convert W -> bf16, zero cnt.
// One launch, tasks split by global thread id.
//   [0, 1600000)            : x float4 -> xcat ushort4   (50000*128/4)
//   [1600000, 1650000)      : cnt = 0
//   [1650000, 1666384)      : W float4 -> Wbf ushort4    (256*256/4)
// ---------------------------------------------------------------------------
#define PREP_X   1600000
#define PREP_C   1650000
#define PREP_W   1666384

__global__ __launch_bounds__(256)
void prep_kernel(const float* __restrict__ x, const float* __restrict__ W,
                 unsigned short* __restrict__ xcat, unsigned short* __restrict__ Wbf,
                 int* __restrict__ cnt) {
    int g = blockIdx.x * 256 + threadIdx.x;
    if (g < PREP_X) {
        float4 v = ((const float4*)x)[g];
        int row = g >> 5;            // 32 float4 per 128-ch row
        int col = (g & 31) * 4;
        *(ushort4*)(xcat + (size_t)row * KTOT + col) =
            make_ushort4(f2bf(v.x), f2bf(v.y), f2bf(v.z), f2bf(v.w));
    } else if (g < PREP_C) {
        cnt[g - PREP_X] = 0;
    } else if (g < PREP_W) {
        int i = g - PREP_C;
        float4 v = ((const float4*)W)[i];
        *(ushort4*)(Wbf + (size_t)i * 4) =
            make_ushort4(f2bf(v.x), f2bf(v.y), f2bf(v.z), f2bf(v.w));
    }
}

// ---------------------------------------------------------------------------
__global__ void hist_kernel(const int* __restrict__ dst, int* __restrict__ cnt, int E) {
    int i = blockIdx.x * blockDim.x + threadIdx.x;
    if (i < E) atomicAdd(&cnt[dst[i]], 1);
}

// single-block chunked exclusive scan: cnt[0..NNODES) -> row_start[0..NNODES]
__global__ __launch_bounds__(1024)
void scan_onepass(const int* __restrict__ cnt, int* __restrict__ row_start) {
    __shared__ int tile[4096];
    __shared__ int tsum[1024];
    const int tid = threadIdx.x;
    int carry = 0;

    for (int c0 = 0; c0 < NNODES; c0 += 4096) {
#pragma unroll
        for (int j = 0; j < 4; ++j) {
            int idx = c0 + j * 1024 + tid;
            tile[j * 1024 + tid] = (idx < NNODES) ? cnt[idx] : 0;
        }
        __syncthreads();
        int a0 = tile[tid * 4 + 0], a1 = tile[tid * 4 + 1];
        int a2 = tile[tid * 4 + 2], a3 = tile[tid * 4 + 3];
        int s = a0 + a1 + a2 + a3;
        tsum[tid] = s;
        __syncthreads();
        for (int off = 1; off < 1024; off <<= 1) {
            int t = (tid >= off) ? tsum[tid - off] : 0;
            __syncthreads();
            tsum[tid] += t;
            __syncthreads();
        }
        int excl = tsum[tid] - s + carry;
        int chunktot = tsum[1023];
        int base = c0 + tid * 4;
        if (base < NNODES) {   // NNODES % 4 == 0 -> whole int4 in-bounds
            *(int4*)&row_start[base] = make_int4(excl, excl + a0, excl + a0 + a1,
                                                 excl + a0 + a1 + a2);
        }
        carry += chunktot;
        // next iteration's tsum writes are fenced by its post-load barrier
    }
    if (tid == 0) row_start[NNODES] = carry;   // == E
}

// rank-scatter: consumes cnt down to zero
__global__ void scatter_kernel(const int* __restrict__ src, const int* __restrict__ dst,
                               const int* __restrict__ row_start, int* __restrict__ cnt,
                               int* __restrict__ sorted_src, int E) {
    int i = blockIdx.x * blockDim.x + threadIdx.x;
    if (i < E) {
        int d = dst[i];
        int pos = atomicSub(&cnt[d], 1) - 1;
        sorted_src[row_start[d] + pos] = src[i];
    }
}

// ---------------------------------------------------------------------------
// gather-max over bf16 neighbor rows (read from xcat x-half, written by prep).
// one wave per node, lane = 2 channels (ushort2 = 4B/lane), 4-way edge ILP.
// max(bf16(v)) == bf16(max(v)) since RNE rounding is monotone.
// writes xj half: xcat[n][128:256] = bf16(max - x[n]) (empty -> 0)
// ---------------------------------------------------------------------------
__device__ __forceinline__ float2 fmax2(float2 a, float2 b) {
    return make_float2(fmaxf(a.x, b.x), fmaxf(a.y, b.y));
}

__global__ __launch_bounds__(256)
void gather_max_kernel(const float* __restrict__ x,
                       const int* __restrict__ row_start,
                       const int* __restrict__ sorted_src,
                       unsigned short* __restrict__ xcat) {
    int wid  = (blockIdx.x * blockDim.x + threadIdx.x) >> 6;
    int lane = threadIdx.x & 63;
    if (wid >= NNODES) return;

    int start = row_start[wid];
    int end   = row_start[wid + 1];

    const float NI = __int_as_float(0xFF800000u);
    float2 m0 = make_float2(NI, NI), m1 = m0, m2 = m0, m3 = m0;

    int t = start;
    for (; t + 4 <= end; t += 4) {
        int s0 = sorted_src[t + 0];
        int s1 = sorted_src[t + 1];
        int s2 = sorted_src[t + 2];
        int s3 = sorted_src[t + 3];
        ushort2 u0 = *(const ushort2*)(xcat + (size_t)s0 * KTOT + lane * 2);
        ushort2 u1 = *(const ushort2*)(xcat + (size_t)s1 * KTOT + lane * 2);
        ushort2 u2 = *(const ushort2*)(xcat + (size_t)s2 * KTOT + lane * 2);
        ushort2 u3 = *(const ushort2*)(xcat + (size_t)s3 * KTOT + lane * 2);
        m0 = fmax2(m0, make_float2(bf2f(u0.x), bf2f(u0.y)));
        m1 = fmax2(m1, make_float2(bf2f(u1.x), bf2f(u1.y)));
        m2 = fmax2(m2, make_float2(bf2f(u2.x), bf2f(u2.y)));
        m3 = fmax2(m3, make_float2(bf2f(u3.x), bf2f(u3.y)));
    }
    for (; t < end; ++t) {
        int s = sorted_src[t];
        ushort2 u = *(const ushort2*)(xcat + (size_t)s * KTOT + lane * 2);
        m0 = fmax2(m0, make_float2(bf2f(u.x), bf2f(u.y)));
    }
    float2 mx = fmax2(fmax2(m0, m1), fmax2(m2, m3));

    float2 xv = ((const float2*)(x + (size_t)wid * CIN))[lane];
    bool nonempty = (end > start);
    float2 o;
    o.x = nonempty ? mx.x - xv.x : 0.0f;
    o.y = nonempty ? mx.y - xv.y : 0.0f;
    *((ushort2*)(xcat + (size_t)wid * KTOT + CIN + lane * 2)) =
        make_ushort2(f2bf(o.x), f2bf(o.y));
}

// ---------------------------------------------------------------------------
// MFMA GEMM: out = relu( xcat[M][256] @ Wbf[256][256]^T + bias )
// BM=64, BN=256 (full), BK=32, 256 threads = 4 waves, each wave a 64x64 n-slice.
// double-buffered LDS, global_load_lds width 16. 782 blocks ~ 3/CU balanced.
// ---------------------------------------------------------------------------
__global__ __launch_bounds__(256, 3)
void mfma_gemm(const unsigned short* __restrict__ xcat,
               const unsigned short* __restrict__ Wbf,
               const float* __restrict__ bias,
               float* __restrict__ out) {
    __shared__ unsigned short As[2][64][32];    //  8 KB
    __shared__ unsigned short Bs[2][256][32];   // 32 KB

    const int M = NNODES;
    const int m0 = blockIdx.x * 64;

    const int tid  = threadIdx.x;
    const int lane = tid & 63;
    const int wid  = tid >> 6;     // n-slice 0..3

    f32x4 acc[4][4] = {};

    auto stage = [&](int b, int kt) {
        {   // A: 64 rows x 32k = 4 KB -> 1 load/thread
            int row  = tid >> 2;
            int kseg = (tid & 3) * 8;
            int grow = m0 + row; if (grow > M - 1) grow = M - 1;
            GLOAD16(xcat + (size_t)grow * KTOT + kt + kseg, &As[b][row][kseg]);
        }
#pragma unroll
        for (int j = 0; j < 4; ++j) {   // B: 256 rows x 32k = 16 KB -> 4/thread
            int u    = j * 256 + tid;
            int row  = u >> 2;
            int kseg = (u & 3) * 8;
            GLOAD16(Wbf + (size_t)row * KTOT + kt + kseg, &Bs[b][row][kseg]);
        }
    };

    stage(0, 0);
    __syncthreads();

    const int l15 = lane & 15;
    const int kh  = (lane >> 4) * 8;

#pragma unroll
    for (int t = 0; t < 8; ++t) {
        int b = t & 1;
        if (t < 7) stage(b ^ 1, (t + 1) * 32);

        bf16x8 af[4], bfr[4];
#pragma unroll
        for (int m = 0; m < 4; ++m)
            af[m] = *(const bf16x8*)&As[b][m * 16 + l15][kh];
#pragma unroll
        for (int n = 0; n < 4; ++n)
            bfr[n] = *(const bf16x8*)&Bs[b][wid * 64 + n * 16 + l15][kh];
#pragma unroll
        for (int m = 0; m < 4; ++m)
#pragma unroll
            for (int n = 0; n < 4; ++n)
                acc[m][n] = __builtin_amdgcn_mfma_f32_16x16x32_bf16(af[m], bfr[n], acc[m][n], 0, 0, 0);

        __syncthreads();
    }

    // epilogue: bias + relu; C/D: col=lane&15, row=(lane>>4)*4+reg
#pragma unroll
    for (int n = 0; n < 4; ++n) {
        int col = wid * 64 + n * 16 + l15;
        float bv = bias[col];
#pragma unroll
        for (int m = 0; m < 4; ++m) {
            int r0 = m0 + m * 16 + ((lane >> 4) << 2);
            f32x4 a = acc[m][n];
#pragma unroll
            for (int r = 0; r < 4; ++r) {
                int rr = r0 + r;
                if (rr < M) out[(size_t)rr * COUT + col] = fmaxf(a[r] + bv, 0.0f);
            }
        }
    }
}

// ---------------------------------------------------------------------------
extern "C" void kernel_launch(void* const* d_in, const int* in_sizes, int n_in,
                              void* d_out, int out_size, void* d_ws, size_t ws_size,
                              hipStream_t stream) {
    const float* x  = (const float*)d_in[0];
    const int*   ei = (const int*)d_in[1];
    const float* W  = (const float*)d_in[2];
    const float* b  = (const float*)d_in[3];
    float*       out = (float*)d_out;

    const int E = in_sizes[1] / 2;
    const int* src = ei;
    const int* dst = ei + E;

    // ws carve-up
    unsigned short* xcat       = (unsigned short*)d_ws;            // [50000][256] bf16
    unsigned short* Wbf        = xcat + (size_t)NNODES * KTOT;     // [256][256] bf16
    int*            cnt        = (int*)(Wbf + COUT * KTOT);
    int*            row_start  = cnt + NNODES;
    int*            sorted_src = row_start + (NNODES + 1);

    const int NB_E = (E + 255) / 256;

    prep_kernel<<<(PREP_W + 255) / 256, 256, 0, stream>>>(x, W, xcat, Wbf, cnt);
    hist_kernel<<<NB_E, 256, 0, stream>>>(dst, cnt, E);
    scan_onepass<<<1, 1024, 0, stream>>>(cnt, row_start);
    scatter_kernel<<<NB_E, 256, 0, stream>>>(src, dst, row_start, cnt, sorted_src, E);
    gather_max_kernel<<<(NNODES * 64 + 255) / 256, 256, 0, stream>>>(x, row_start, sorted_src, xcat);
    mfma_gemm<<<(NNODES + 63) / 64, 256, 0, stream>>>(xcat, Wbf, b, out);
}

// Round 6
// 208.664 us; speedup vs baseline: 1.1256x; 1.1256x over previous
//
#include <hip/hip_runtime.h>

#define NNODES 50000
#define CIN    128
#define COUT   256
#define KTOT   256   // 2*CIN

typedef float  f32x4  __attribute__((ext_vector_type(4)));
typedef short  bf16x8 __attribute__((ext_vector_type(8)));

#define GLOAD16(gptr, lptr) __builtin_amdgcn_global_load_lds(                      \
    (const __attribute__((address_space(1))) void*)(gptr),                         \
    (__attribute__((address_space(3))) void*)(lptr), 16, 0, 0)

__device__ __forceinline__ unsigned short f2bf(float f) {
    union { float f; unsigned int u; } v; v.f = f;
    unsigned int r = v.u + 0x7FFFu + ((v.u >> 16) & 1u);   // RNE
    return (unsigned short)(r >> 16);
}
__device__ __forceinline__ float bf2f(unsigned short u) {
    return __uint_as_float((unsigned int)u << 16);
}

// ---------------------------------------------------------------------------
// prep: convert x -> bf16 into xcat[:,0:128], convert W -> bf16, zero cnt.
//   [0, 1600000)       : x float4 -> xcat ushort4   (50000*128/4)
//   [1600000, 1650000) : cnt = 0
//   [1650000, 1666384) : W float4 -> Wbf ushort4    (256*256/4)
// ---------------------------------------------------------------------------
#define PREP_X   1600000
#define PREP_C   1650000
#define PREP_W   1666384

__global__ __launch_bounds__(256)
void prep_kernel(const float* __restrict__ x, const float* __restrict__ W,
                 unsigned short* __restrict__ xcat, unsigned short* __restrict__ Wbf,
                 int* __restrict__ cnt) {
    int g = blockIdx.x * 256 + threadIdx.x;
    if (g < PREP_X) {
        float4 v = ((const float4*)x)[g];
        int row = g >> 5;            // 32 float4 per 128-ch row
        int col = (g & 31) * 4;
        *(ushort4*)(xcat + (size_t)row * KTOT + col) =
            make_ushort4(f2bf(v.x), f2bf(v.y), f2bf(v.z), f2bf(v.w));
    } else if (g < PREP_C) {
        cnt[g - PREP_X] = 0;
    } else if (g < PREP_W) {
        int i = g - PREP_C;
        float4 v = ((const float4*)W)[i];
        *(ushort4*)(Wbf + (size_t)i * 4) =
            make_ushort4(f2bf(v.x), f2bf(v.y), f2bf(v.z), f2bf(v.w));
    }
}

// ---------------------------------------------------------------------------
__global__ void hist_kernel(const int* __restrict__ dst, int* __restrict__ cnt, int E) {
    int i = blockIdx.x * blockDim.x + threadIdx.x;
    if (i < E) atomicAdd(&cnt[dst[i]], 1);
}

// 196-block partial sums: partial[b] = sum(cnt[b*256 .. b*256+255])
__global__ __launch_bounds__(256)
void scan_partial(const int* __restrict__ cnt, int* __restrict__ partial, int n) {
    __shared__ int s[256];
    int tid = threadIdx.x;
    int i = blockIdx.x * 256 + tid;
    s[tid] = (i < n) ? cnt[i] : 0;
    __syncthreads();
    for (int off = 128; off > 0; off >>= 1) {
        if (tid < off) s[tid] += s[tid + off];
        __syncthreads();
    }
    if (tid == 0) partial[blockIdx.x] = s[0];
}

// 196-block finalize: each block scans all 196 partials in-LDS (redundant,
// cheap) to get its base, then local scan of its 256 cnt values.
__global__ __launch_bounds__(256)
void scan_final(const int* __restrict__ cnt, const int* __restrict__ partial,
                int* __restrict__ row_start, int nb) {
    __shared__ int ps[256];
    __shared__ int s[256];
    const int tid = threadIdx.x;

    ps[tid] = (tid < nb) ? partial[tid] : 0;
    __syncthreads();
    for (int off = 1; off < 256; off <<= 1) {
        int t = (tid >= off) ? ps[tid - off] : 0;
        __syncthreads();
        ps[tid] += t;
        __syncthreads();
    }
    int base = (blockIdx.x == 0) ? 0 : ps[blockIdx.x - 1];

    int i = blockIdx.x * 256 + tid;
    int v = (i < NNODES) ? cnt[i] : 0;
    s[tid] = v;
    __syncthreads();
    for (int off = 1; off < 256; off <<= 1) {
        int t = (tid >= off) ? s[tid - off] : 0;
        __syncthreads();
        s[tid] += t;
        __syncthreads();
    }
    if (i < NNODES) row_start[i] = base + s[tid] - v;
    if (i == NNODES - 1) row_start[NNODES] = base + s[tid];   // == E
}

// rank-scatter: consumes cnt down to zero
__global__ void scatter_kernel(const int* __restrict__ src, const int* __restrict__ dst,
                               const int* __restrict__ row_start, int* __restrict__ cnt,
                               int* __restrict__ sorted_src, int E) {
    int i = blockIdx.x * blockDim.x + threadIdx.x;
    if (i < E) {
        int d = dst[i];
        int pos = atomicSub(&cnt[d], 1) - 1;
        sorted_src[row_start[d] + pos] = src[i];
    }
}

// ---------------------------------------------------------------------------
// gather-max over bf16 neighbor rows (xcat x-half). one wave per node,
// lane = 2 channels (ushort2 = 4B/lane), 8-way edge ILP.
// max(bf16(v)) == bf16(max(v)) since RNE rounding is monotone.
// writes xcat[n][128:256] = bf16(max - x[n]) (empty -> 0)
// ---------------------------------------------------------------------------
__device__ __forceinline__ float2 fmax2(float2 a, float2 b) {
    return make_float2(fmaxf(a.x, b.x), fmaxf(a.y, b.y));
}

__global__ __launch_bounds__(256)
void gather_max_kernel(const float* __restrict__ x,
                       const int* __restrict__ row_start,
                       const int* __restrict__ sorted_src,
                       unsigned short* __restrict__ xcat) {
    int wid  = (blockIdx.x * blockDim.x + threadIdx.x) >> 6;
    int lane = threadIdx.x & 63;
    if (wid >= NNODES) return;

    int start = row_start[wid];
    int end   = row_start[wid + 1];

    const float NI = __int_as_float(0xFF800000u);
    float2 mm[8];
#pragma unroll
    for (int j = 0; j < 8; ++j) mm[j] = make_float2(NI, NI);

    int t = start;
    for (; t + 8 <= end; t += 8) {
        int     si[8];
        ushort2 uu[8];
#pragma unroll
        for (int j = 0; j < 8; ++j) si[j] = sorted_src[t + j];
#pragma unroll
        for (int j = 0; j < 8; ++j)
            uu[j] = *(const ushort2*)(xcat + (size_t)si[j] * KTOT + lane * 2);
#pragma unroll
        for (int j = 0; j < 8; ++j)
            mm[j] = fmax2(mm[j], make_float2(bf2f(uu[j].x), bf2f(uu[j].y)));
    }
    for (; t < end; ++t) {
        int s = sorted_src[t];
        ushort2 u = *(const ushort2*)(xcat + (size_t)s * KTOT + lane * 2);
        mm[0] = fmax2(mm[0], make_float2(bf2f(u.x), bf2f(u.y)));
    }
    float2 mx = fmax2(fmax2(fmax2(mm[0], mm[1]), fmax2(mm[2], mm[3])),
                      fmax2(fmax2(mm[4], mm[5]), fmax2(mm[6], mm[7])));

    float2 xv = ((const float2*)(x + (size_t)wid * CIN))[lane];
    bool nonempty = (end > start);
    float2 o;
    o.x = nonempty ? mx.x - xv.x : 0.0f;
    o.y = nonempty ? mx.y - xv.y : 0.0f;
    *((ushort2*)(xcat + (size_t)wid * KTOT + CIN + lane * 2)) =
        make_ushort2(f2bf(o.x), f2bf(o.y));
}

// ---------------------------------------------------------------------------
// MFMA GEMM: out = relu( xcat[M][256] @ Wbf[256][256]^T + bias )
// BM=64, BN=256, BK=32, 4 waves, each wave a 64x64 n-slice.
// LDS bank-conflict fix: pre-swizzled global SOURCE (LDS dest stays linear,
// per m104/m173): element slot kseg holds global k = kseg ^ ((row&3)<<3).
// Fragment reads apply the same XOR -> 8-way conflict becomes 4-way.
// ---------------------------------------------------------------------------
__global__ __launch_bounds__(256, 3)
void mfma_gemm(const unsigned short* __restrict__ xcat,
               const unsigned short* __restrict__ Wbf,
               const float* __restrict__ bias,
               float* __restrict__ out) {
    __shared__ unsigned short As[2][64][32];    //  8 KB
    __shared__ unsigned short Bs[2][256][32];   // 32 KB

    const int M = NNODES;
    const int m0 = blockIdx.x * 64;

    const int tid  = threadIdx.x;
    const int lane = tid & 63;
    const int wid  = tid >> 6;     // n-slice 0..3

    f32x4 acc[4][4] = {};

    auto stage = [&](int b, int kt) {
        {   // A: 64 rows x 32k -> 1 load/thread; LDS addr linear in tid
            int row  = tid >> 2;
            int kseg = (tid & 3) * 8;
            int ks   = kseg ^ ((row & 3) << 3);      // swizzled source slot
            int grow = m0 + row; if (grow > M - 1) grow = M - 1;
            GLOAD16(xcat + (size_t)grow * KTOT + kt + ks, &As[b][row][kseg]);
        }
#pragma unroll
        for (int j = 0; j < 4; ++j) {   // B: 256 rows x 32k -> 4/thread
            int u    = j * 256 + tid;
            int row  = u >> 2;
            int kseg = (u & 3) * 8;
            int ks   = kseg ^ ((row & 3) << 3);
            GLOAD16(Wbf + (size_t)row * KTOT + kt + ks, &Bs[b][row][kseg]);
        }
    };

    stage(0, 0);
    __syncthreads();

    const int l15 = lane & 15;
    const int kh  = (lane >> 4) * 8;
    const int khs = kh ^ ((l15 & 3) << 3);   // swizzled read slot (row&3 == l15&3)

#pragma unroll
    for (int t = 0; t < 8; ++t) {
        int b = t & 1;
        if (t < 7) stage(b ^ 1, (t + 1) * 32);

        bf16x8 af[4], bfr[4];
#pragma unroll
        for (int m = 0; m < 4; ++m)
            af[m] = *(const bf16x8*)&As[b][m * 16 + l15][khs];
#pragma unroll
        for (int n = 0; n < 4; ++n)
            bfr[n] = *(const bf16x8*)&Bs[b][wid * 64 + n * 16 + l15][khs];
#pragma unroll
        for (int m = 0; m < 4; ++m)
#pragma unroll
            for (int n = 0; n < 4; ++n)
                acc[m][n] = __builtin_amdgcn_mfma_f32_16x16x32_bf16(af[m], bfr[n], acc[m][n], 0, 0, 0);

        __syncthreads();
    }

    // epilogue: bias + relu; C/D: col=lane&15, row=(lane>>4)*4+reg
#pragma unroll
    for (int n = 0; n < 4; ++n) {
        int col = wid * 64 + n * 16 + l15;
        float bv = bias[col];
#pragma unroll
        for (int m = 0; m < 4; ++m) {
            int r0 = m0 + m * 16 + ((lane >> 4) << 2);
            f32x4 a = acc[m][n];
#pragma unroll
            for (int r = 0; r < 4; ++r) {
                int rr = r0 + r;
                if (rr < M) out[(size_t)rr * COUT + col] = fmaxf(a[r] + bv, 0.0f);
            }
        }
    }
}

// ---------------------------------------------------------------------------
extern "C" void kernel_launch(void* const* d_in, const int* in_sizes, int n_in,
                              void* d_out, int out_size, void* d_ws, size_t ws_size,
                              hipStream_t stream) {
    const float* x  = (const float*)d_in[0];
    const int*   ei = (const int*)d_in[1];
    const float* W  = (const float*)d_in[2];
    const float* b  = (const float*)d_in[3];
    float*       out = (float*)d_out;

    const int E = in_sizes[1] / 2;
    const int* src = ei;
    const int* dst = ei + E;

    // ws carve-up
    unsigned short* xcat       = (unsigned short*)d_ws;            // [50000][256] bf16
    unsigned short* Wbf        = xcat + (size_t)NNODES * KTOT;     // [256][256] bf16
    int*            cnt        = (int*)(Wbf + COUT * KTOT);
    int*            row_start  = cnt + NNODES;
    int*            sorted_src = row_start + (NNODES + 1);
    int*            partial    = sorted_src + E;                   // 196 ints

    const int NB_N = (NNODES + 255) / 256;   // 196
    const int NB_E = (E + 255) / 256;

    prep_kernel<<<(PREP_W + 255) / 256, 256, 0, stream>>>(x, W, xcat, Wbf, cnt);
    hist_kernel<<<NB_E, 256, 0, stream>>>(dst, cnt, E);
    scan_partial<<<NB_N, 256, 0, stream>>>(cnt, partial, NNODES);
    scan_final<<<NB_N, 256, 0, stream>>>(cnt, partial, row_start, NB_N);
    scatter_kernel<<<NB_E, 256, 0, stream>>>(src, dst, row_start, cnt, sorted_src, E);
    gather_max_kernel<<<(NNODES * 64 + 255) / 256, 256, 0, stream>>>(x, row_start, sorted_src, xcat);
    mfma_gemm<<<(NNODES + 63) / 64, 256, 0, stream>>>(xcat, Wbf, b, out);
}